// Round 11
// baseline (434.084 us; speedup 1.0000x reference)
//
#include <hip/hip_runtime.h>
#include <hip/hip_fp16.h>

#define NN 50000
#define EE 800000
#define NB 782      // blocks in mm1/mm2 grids
#define NBKT 196    // dst>>8 buckets (256 nodes each)
#define BCAP 4608   // staging capacity per bucket (mean 4081, sigma ~64)

typedef _Float16 f16x8 __attribute__((ext_vector_type(8)));
typedef _Float16 f16x2 __attribute__((ext_vector_type(2)));
typedef float f32x4 __attribute__((ext_vector_type(4)));

// bit-cast helpers
__device__ __forceinline__ unsigned h2u(__half2 h) {
    union { __half2 h; unsigned u; } c; c.h = h; return c.u;
}
__device__ __forceinline__ f16x2 u2h(unsigned u) {
    union { unsigned u; f16x2 h; } c; c.u = u; return c.h;
}
__device__ __forceinline__ unsigned f2u(f16x2 h) {
    union { f16x2 h; unsigned u; } c; c.h = h; return c.u;
}

// ---------------------------------------------------------------------------
// CSR build, bucketed: bin -> bcountA (deg + raw bucket sums) -> scanC
// (bucket scan recomputed in-block + node scan -> off) -> place2.
// Dummy edge = {ea=0, src=50000}; h16 row 50000 = -65504 so
// relu(h_dummy + ee) == 0 -> maskless gather.
// ---------------------------------------------------------------------------
__global__ __launch_bounds__(256) void bin_kernel(
    const int* __restrict__ ei, const float* __restrict__ ea,
    int* __restrict__ bktcur, int4* __restrict__ srec,
    unsigned short* __restrict__ sdst)
{
    __shared__ int cnt[NBKT], base[NBKT];
    const int t = threadIdx.x;
    if (t < NBKT) cnt[t] = 0;
    __syncthreads();
    const int e0 = blockIdx.x << 12;     // 4096 edges/block, 196 blocks
    int meta[16];                        // rk<<16 | bk<<8 | loc  (rk<4096)
#pragma unroll
    for (int j = 0; j < 16; ++j) {
        const int e = e0 + (j << 8) + t;
        if (e < EE) {
            const int d = ei[EE + e];
            const int bk = d >> 8;
            const int rk = atomicAdd(&cnt[bk], 1);
            meta[j] = (rk << 16) | (bk << 8) | (d & 255);
        } else meta[j] = -1;
    }
    __syncthreads();
    if (t < NBKT) base[t] = cnt[t] ? atomicAdd(&bktcur[t], cnt[t]) : 0;
    __syncthreads();
#pragma unroll
    for (int j = 0; j < 16; ++j) {
        if (meta[j] < 0) continue;
        const int bk = (meta[j] >> 8) & 255;
        const int slot = base[bk] + (meta[j] >> 16);
        if (slot >= BCAP) continue;      // statistically impossible guard
        const int pos = bk * BCAP + slot;
        const int e = e0 + (j << 8) + t;
        const int src = ei[e];
        const float* a = ea + e * 7;
        const unsigned h0 = __half_as_ushort(__float2half(a[0]));
        const unsigned h1 = __half_as_ushort(__float2half(a[1]));
        const unsigned h2 = __half_as_ushort(__float2half(a[2]));
        const unsigned h3 = __half_as_ushort(__float2half(a[3]));
        const unsigned h4 = __half_as_ushort(__float2half(a[4]));
        const unsigned h5 = __half_as_ushort(__float2half(a[5]));
        const unsigned h6 = __half_as_ushort(__float2half(a[6]));
        srec[pos] = make_int4((int)(h0 | (h1 << 16)), (int)(h2 | (h3 << 16)),
                              (int)(h4 | (h5 << 16)), (int)(h6 | ((unsigned)src << 16)));
        sdst[pos] = (unsigned short)(meta[j] & 255);
    }
}

// per-bucket LDS histogram -> deg, + RAW padded bucket sum (folds scanA)
__global__ __launch_bounds__(256) void bcountA_kernel(
    const int* __restrict__ bktcur, const unsigned short* __restrict__ sdst,
    int* __restrict__ deg, int* __restrict__ bsum)
{
    __shared__ int nc[256], sm[256];
    const int b = blockIdx.x, t = threadIdx.x;
    nc[t] = 0;
    __syncthreads();
    const int nE = min(bktcur[b], BCAP);
    const int sb = b * BCAP;
    for (int i = t; i < nE; i += 256) atomicAdd(&nc[(int)sdst[sb + i]], 1);
    __syncthreads();
    const int node = (b << 8) + t;
    if (node < NN) deg[node] = nc[t];
    sm[t] = (node < NN) ? ((nc[t] + 7) & ~7) : 0;
    __syncthreads();
    for (int o = 128; o > 0; o >>= 1) {
        if (t < o) sm[t] += sm[t + o];
        __syncthreads();
    }
    if (t == 0) bsum[b] = sm[0];
}

// off[] build: in-block exclusive scan of the 196 raw bucket sums (replaces
// scanB dispatch) + node-level scan of padded degrees.
__global__ __launch_bounds__(256) void scanC_kernel(const int* __restrict__ deg,
                                                    const int* __restrict__ bsum,
                                                    int* __restrict__ off) {
    __shared__ int sm[256], bs[256], bsr[256];
    const int t = threadIdx.x;
    const int bv = (t < NBKT) ? bsum[t] : 0;
    bs[t] = bv; bsr[t] = bv;
    __syncthreads();
    for (int o = 1; o < 256; o <<= 1) {
        const int u = (t >= o) ? bs[t - o] : 0;
        __syncthreads();
        bs[t] += u;
        __syncthreads();
    }
    const int i = (blockIdx.x << 8) + t;
    const int v = (i < NN) ? ((deg[i] + 7) & ~7) : 0;
    sm[t] = v;
    __syncthreads();
    for (int o = 1; o < 256; o <<= 1) {
        const int u = (t >= o) ? sm[t - o] : 0;
        __syncthreads();
        sm[t] += u;
        __syncthreads();
    }
    const int gbase = bs[blockIdx.x] - bsr[blockIdx.x];   // exclusive prefix
    const int excl = gbase + sm[t] - v;
    if (i < NN) off[i] = excl;
    else if (i == NN) off[NN] = excl;
}

// placement: LDS cursors from off; records into bucket's pea slice; dummy fill
__global__ __launch_bounds__(256) void place2_kernel(
    const int* __restrict__ bktcur, const int* __restrict__ off,
    const int4* __restrict__ srec, const unsigned short* __restrict__ sdst,
    int4* __restrict__ pea)
{
    __shared__ int curs[256];
    const int b = blockIdx.x, t = threadIdx.x;
    const int node = (b << 8) + t;
    curs[t] = (node < NN) ? off[node] : 0;
    __syncthreads();
    const int nE = min(bktcur[b], BCAP);
    const int sb = b * BCAP;
    for (int i = t; i < nE; i += 256) {
        const int ln = (int)sdst[sb + i];
        const int p = atomicAdd(&curs[ln], 1);
        pea[p] = srec[sb + i];           // random only within ~82KB L2-hot slice
    }
    __syncthreads();
    if (node < NN) {
        const int end = off[node + 1];
        for (int p = curs[t]; p < end; ++p)   // dummy tail: relu(h_dummy+ee)==0
            pea[p] = make_int4(0, 0, 0, (int)(((unsigned)NN) << 16));
    }
}

// ---------------------------------------------------------------------------
// Prep (merged wprep + hprep0): blocks 0..3124 do layer-0 h16 = f16(nemb[x])
// (+ dummy row -65504, + z16 tail zero); blocks 3125..3449 do W prep.
// ---------------------------------------------------------------------------
__global__ __launch_bounds__(256) void prep_kernel(
    const int* __restrict__ x, const float* __restrict__ nemb,
    __half* __restrict__ h16, unsigned* __restrict__ z32,
    const float* __restrict__ W1, const float* __restrict__ W2,
    const float* __restrict__ We, const float* __restrict__ be,
    _Float16* __restrict__ W1s, _Float16* __restrict__ W2s,
    unsigned* __restrict__ Wepk, unsigned* __restrict__ be2)
{
    if (blockIdx.x < 3125) {
        const int i4 = (blockIdx.x << 8) + threadIdx.x;   // NN*64/4
        if (blockIdx.x == 0 && threadIdx.x < 32)
            ((unsigned*)h16)[(NN << 5) + threadIdx.x] = 0xFBFFFBFFu;
        if (i4 < 1536) z32[1600000 + i4] = 0u;   // zero z16 rows 50000..50047
        const int n = i4 >> 4;
        const float4 v = ((const float4*)nemb)[(x[n] << 4) + (i4 & 15)];
        *(int2*)(h16 + (i4 << 2)) =
            make_int2((int)h2u(__floats2half2_rn(v.x, v.y)),
                      (int)h2u(__floats2half2_rn(v.z, v.w)));
        return;
    }
    const int i = ((blockIdx.x - 3125) << 8) + threadIdx.x;
    if (i < 40960) {
        const int l = i >> 13, j = i & 8191, k = j >> 7, n = j & 127;
        W1s[(l << 13) + ((((k >> 3) << 7) + n) << 3) + (k & 7)] = (_Float16)W1[i];
    } else if (i < 81920) {
        const int i2 = i - 40960;
        const int l = i2 >> 13, j = i2 & 8191, k = j >> 6, n = j & 63;
        W2s[(l << 13) + ((((k >> 3) << 6) + n) << 3) + (k & 7)] = (_Float16)W2[i2];
    } else if (i < 83040) {
        const int i3 = i - 81920;            // 0..1119 = [l][k][s]
        const int l = i3 / 224;
        const int r = i3 - l * 224;
        const int k = r >> 5, s = r & 31;
        const float* W = We + l * 448 + (k << 6) + (s << 1);
        Wepk[i3] = h2u(__floats2half2_rn(W[0], W[1]));
    } else if (i < 83200) {
        const int i4 = i - 83040;            // 0..159 = [l][s]
        const int l = i4 >> 5, s = i4 & 31;
        const float* B = be + (l << 6) + (s << 1);
        be2[i4] = h2u(__floats2half2_rn(B[0], B[1]));
    }
}

// ---------------------------------------------------------------------------
// h-prep: h16 = f16(relu(bn2(y2))). BN2 scale/shift computed in-block from
// the 8-way-split atomic accumulators (acc2: 8 copies x [s64|q64]).
// ---------------------------------------------------------------------------
__global__ __launch_bounds__(256) void hprep_kernel(
    const float* __restrict__ y2, const float* __restrict__ acc2,
    const float* __restrict__ g2p, const float* __restrict__ bb2p,
    __half* __restrict__ h16)
{
    __shared__ float scshL[128];
    const int t = threadIdx.x;
    if (t < 64) {
        float ss = 0.f, qq = 0.f;
#pragma unroll
        for (int c = 0; c < 8; ++c) {
            ss += acc2[(c << 7) + t];
            qq += acc2[(c << 7) + 64 + t];
        }
        const float m = ss * (1.0f / NN);
        const float v = fmaxf(qq * (1.0f / NN) - m * m, 0.0f);
        const float sc = g2p[t] * rsqrtf(v + 1e-5f);
        scshL[t] = sc;
        scshL[64 + t] = bb2p[t] - m * sc;
    }
    __syncthreads();
    const int i4 = (blockIdx.x << 8) + t;             // 3125*256 == NN*64/4
    const float4 v = ((const float4*)y2)[i4];
    const int d0 = (i4 << 2) & 63;
    const float a = fmaxf(fmaf(v.x, scshL[d0 + 0], scshL[64 + d0 + 0]), 0.f);
    const float b = fmaxf(fmaf(v.y, scshL[d0 + 1], scshL[64 + d0 + 1]), 0.f);
    const float c = fmaxf(fmaf(v.z, scshL[d0 + 2], scshL[64 + d0 + 2]), 0.f);
    const float d = fmaxf(fmaf(v.w, scshL[d0 + 3], scshL[64 + d0 + 3]), 0.f);
    *(int2*)(h16 + (i4 << 2)) =
        make_int2((int)h2u(__floats2half2_rn(a, b)),
                  (int)h2u(__floats2half2_rn(c, d)));
}

// ---------------------------------------------------------------------------
// Gather v3 (half-wave edge-split): ONE node per wave; lanes 0-31 process
// even 8-edge batches, lanes 32-63 odd batches (same dims s=lane&31);
// combine via one shfl_xor(32). Doubles batch ILP and block count (load
// balance) at ~65 VGPR -> near-max occupancy. Maskless (padded CSR).
// ---------------------------------------------------------------------------
__global__ __launch_bounds__(256) void gather_kernel(
    const int* __restrict__ off, const int4* __restrict__ pea,
    const unsigned* __restrict__ h32,      // h16 rows viewed as 32 dwords
    const unsigned* __restrict__ Wepk, const unsigned* __restrict__ be2,
    const float* __restrict__ epsp,
    unsigned* __restrict__ z32)            // z16 rows viewed as 32 dwords
{
    const int t = threadIdx.x;
    const int lane = t & 63;
    const int s = lane & 31;
    const int hh = lane >> 5;
    const int n = (blockIdx.x << 2) + (t >> 6);   // 12500*4 == 50000

    const f16x2 w0 = u2h(Wepk[s]),       w1 = u2h(Wepk[32 + s]),
                w2 = u2h(Wepk[64 + s]),  w3 = u2h(Wepk[96 + s]),
                w4 = u2h(Wepk[128 + s]), w5 = u2h(Wepk[160 + s]),
                w6 = u2h(Wepk[192 + s]);
    const f16x2 beh = u2h(be2[s]);

    const int e0 = off[n], e1 = off[n + 1];   // padded: count % 8 == 0

    f16x2 acc2 = (f16x2){(_Float16)0.f, (_Float16)0.f};
    for (int e = e0 + (hh << 3); e < e1; e += 16) {
        int4 pk[8];
#pragma unroll
        for (int j = 0; j < 8; ++j) pk[j] = pea[e + j];
        unsigned hv[8];
#pragma unroll
        for (int j = 0; j < 8; ++j) {
            const int src = (int)(((unsigned)pk[j].w) >> 16);
            hv[j] = h32[(src << 5) + s];
        }
#pragma unroll
        for (int j = 0; j < 8; ++j) {
            const f16x2 a01 = u2h((unsigned)pk[j].x);
            const f16x2 a23 = u2h((unsigned)pk[j].y);
            const f16x2 a45 = u2h((unsigned)pk[j].z);
            const f16x2 a6x = u2h((unsigned)pk[j].w);
            f16x2 ee = beh;
            ee += (f16x2){a01[0], a01[0]} * w0;
            ee += (f16x2){a01[1], a01[1]} * w1;
            ee += (f16x2){a23[0], a23[0]} * w2;
            ee += (f16x2){a23[1], a23[1]} * w3;
            ee += (f16x2){a45[0], a45[0]} * w4;
            ee += (f16x2){a45[1], a45[1]} * w5;
            ee += (f16x2){a6x[0], a6x[0]} * w6;
            f16x2 m2 = u2h(hv[j]) + ee;
            const _Float16 zz = (_Float16)0.f;
            m2 = (f16x2){ m2[0] > zz ? m2[0] : zz, m2[1] > zz ? m2[1] : zz };
            acc2 += m2;
        }
    }
    // combine halves: both halves end with the full edge sum for dims (s)
    acc2 += u2h((unsigned)__shfl_xor((int)f2u(acc2), 32));
    if (hh == 0) {
        const f16x2 hn2 = u2h(h32[(n << 5) + s]);
        const float e1f = 1.0f + epsp[0];
        const float zLo = fmaf(e1f, (float)hn2[0], (float)acc2[0]);
        const float zHi = fmaf(e1f, (float)hn2[1], (float)acc2[1]);
        z32[(n << 5) + s] = h2u(__floats2half2_rn(zLo, zHi));
    }
}

// ---------------------------------------------------------------------------
// MM1 (MFMA f16): y1 = z16 @ W1 + b1, f16 out. Block = 64 rows, 4 waves.
// BN1 block sums -> 8-way-split global f32 atomics (no fence).
// ---------------------------------------------------------------------------
__global__ __launch_bounds__(256) void mm1_kernel(
    const _Float16* __restrict__ z16, const _Float16* __restrict__ W1s,
    const float* __restrict__ b1p, _Float16* __restrict__ y1h,
    float* __restrict__ acc1)
{
    __shared__ float smS[4][128], smQ[4][128];
    const int t = threadIdx.x;
    const int wv = t >> 6, lane = t & 63;
    const int q = lane >> 4, ln = lane & 15;
    const int r0 = blockIdx.x << 6;

    const int rowm = r0 + (wv << 4) + ln;
    const f16x8 af0 = *(const f16x8*)(z16 + rowm * 64 + (q << 3));
    const f16x8 af1 = *(const f16x8*)(z16 + rowm * 64 + 32 + (q << 3));

    f32x4 acc[8];
#pragma unroll
    for (int n0 = 0; n0 < 8; ++n0) acc[n0] = (f32x4){0.f, 0.f, 0.f, 0.f};
#pragma unroll
    for (int n0 = 0; n0 < 8; ++n0) {
        const f16x8 bf0 = *(const f16x8*)(W1s + (((q << 7) + (n0 << 4) + ln) << 3));
        const f16x8 bf1 = *(const f16x8*)(W1s + ((((4 + q) << 7) + (n0 << 4) + ln) << 3));
        acc[n0] = __builtin_amdgcn_mfma_f32_16x16x32_f16(af0, bf0, acc[n0], 0, 0, 0);
        acc[n0] = __builtin_amdgcn_mfma_f32_16x16x32_f16(af1, bf1, acc[n0], 0, 0, 0);
    }

    const int baseRow = r0 + (wv << 4) + (q << 2);
#pragma unroll
    for (int n0 = 0; n0 < 8; ++n0) {
        const int col = (n0 << 4) + ln;
        const float bb = b1p[col];
        float s = 0.f, sq = 0.f;
#pragma unroll
        for (int rg = 0; rg < 4; ++rg) {
            const int row = baseRow + rg;
            const float y = acc[n0][rg] + bb;
            y1h[row * 128 + col] = (_Float16)y;
            const float m = (row < NN) ? 1.f : 0.f;
            s = fmaf(m, y, s); sq = fmaf(m, y * y, sq);
        }
        s += __shfl_xor(s, 16); s += __shfl_xor(s, 32);
        sq += __shfl_xor(sq, 16); sq += __shfl_xor(sq, 32);
        if (lane < 16) { smS[wv][col] = s; smQ[wv][col] = sq; }
    }
    __syncthreads();
    if (t < 128) {
        const float s4 = smS[0][t] + smS[1][t] + smS[2][t] + smS[3][t];
        const float q4 = smQ[0][t] + smQ[1][t] + smQ[2][t] + smQ[3][t];
        float* a1 = acc1 + ((blockIdx.x & 7) << 8);
        atomicAdd(&a1[t], s4);
        atomicAdd(&a1[128 + t], q4);
    }
}

// ---------------------------------------------------------------------------
// MM2 (MFMA f16): y2 = relu(bn1(y1h)) @ W2 + b2 (f32 out). Block = 64 rows.
// Prologue: per-block reduce of acc1 -> scsh1 in LDS. Epilogue: BN2 -> acc2.
// ---------------------------------------------------------------------------
__global__ __launch_bounds__(256) void mm2_kernel(
    const _Float16* __restrict__ y1h, const float* __restrict__ acc1,
    const float* __restrict__ g1p, const float* __restrict__ bb1p,
    const _Float16* __restrict__ W2s, const float* __restrict__ b2,
    float* __restrict__ y2, float* __restrict__ acc2)
{
    __shared__ float smS[4][64], smQ[4][64];
    __shared__ float scshL[256];
    const int t = threadIdx.x;
    const int wv = t >> 6, lane = t & 63;
    const int q = lane >> 4, ln = lane & 15;
    const int r0 = blockIdx.x << 6;

    if (t < 128) {                       // finalize BN1 from acc1 (3KB read)
        float ss = 0.f, qq = 0.f;
#pragma unroll
        for (int c = 0; c < 8; ++c) {
            ss += acc1[(c << 8) + t];
            qq += acc1[(c << 8) + 128 + t];
        }
        const float m = ss * (1.0f / NN);
        const float v = fmaxf(qq * (1.0f / NN) - m * m, 0.0f);
        const float sc = g1p[t] * rsqrtf(v + 1e-5f);
        scshL[t] = sc;
        scshL[128 + t] = bb1p[t] - m * sc;
    }
    __syncthreads();

    const int rowm = r0 + (wv << 4) + ln;
    f16x8 af[4];
#pragma unroll
    for (int ks = 0; ks < 4; ++ks) {
        const int k0 = (ks << 5) + (q << 3);
        const f16x8 raw = *(const f16x8*)(y1h + rowm * 128 + k0);
        f16x8 a;
#pragma unroll
        for (int j = 0; j < 8; ++j) {
            const float sc = scshL[k0 + j], sh = scshL[128 + k0 + j];
            a[j] = (_Float16)fmaxf(fmaf((float)raw[j], sc, sh), 0.f);
        }
        af[ks] = a;
    }

    f32x4 acc[4];
#pragma unroll
    for (int n0 = 0; n0 < 4; ++n0) acc[n0] = (f32x4){0.f, 0.f, 0.f, 0.f};
#pragma unroll
    for (int n0 = 0; n0 < 4; ++n0) {
#pragma unroll
        for (int ks = 0; ks < 4; ++ks) {
            const f16x8 bf = *(const f16x8*)(
                W2s + (((((ks << 2) + q) << 6) + (n0 << 4) + ln) << 3));
            acc[n0] = __builtin_amdgcn_mfma_f32_16x16x32_f16(af[ks], bf, acc[n0], 0, 0, 0);
        }
    }

    const int baseRow = r0 + (wv << 4) + (q << 2);
#pragma unroll
    for (int n0 = 0; n0 < 4; ++n0) {
        const int col = (n0 << 4) + ln;
        const float bb = b2[col];
        float sa = 0.f, sq = 0.f;
#pragma unroll
        for (int rg = 0; rg < 4; ++rg) {
            const int row = baseRow + rg;
            const float y = acc[n0][rg] + bb;
            y2[row * 64 + col] = y;
            const float m = (row < NN) ? 1.f : 0.f;
            sa = fmaf(m, y, sa); sq = fmaf(m, y * y, sq);
        }
        sa += __shfl_xor(sa, 16); sa += __shfl_xor(sa, 32);
        sq += __shfl_xor(sq, 16); sq += __shfl_xor(sq, 32);
        if (lane < 16) { smS[wv][col] = sa; smQ[wv][col] = sq; }
    }
    __syncthreads();
    if (t < 64) {
        const float s4 = smS[0][t] + smS[1][t] + smS[2][t] + smS[3][t];
        const float q4 = smQ[0][t] + smQ[1][t] + smQ[2][t] + smQ[3][t];
        float* a2 = acc2 + ((blockIdx.x & 7) << 7);
        atomicAdd(&a2[t], s4);
        atomicAdd(&a2[64 + t], q4);
    }
}

// ---------------------------------------------------------------------------
// Final: out = bn2(y2) of layer 4 (no relu). BN2 finalized in-block.
// ---------------------------------------------------------------------------
__global__ __launch_bounds__(256) void final_kernel(
    const float* __restrict__ y2, const float* __restrict__ acc2,
    const float* __restrict__ g2p, const float* __restrict__ bb2p,
    float* __restrict__ out)
{
    __shared__ float scshL[128];
    const int t = threadIdx.x;
    if (t < 64) {
        float ss = 0.f, qq = 0.f;
#pragma unroll
        for (int c = 0; c < 8; ++c) {
            ss += acc2[(c << 7) + t];
            qq += acc2[(c << 7) + 64 + t];
        }
        const float m = ss * (1.0f / NN);
        const float v = fmaxf(qq * (1.0f / NN) - m * m, 0.0f);
        const float sc = g2p[t] * rsqrtf(v + 1e-5f);
        scshL[t] = sc;
        scshL[64 + t] = bb2p[t] - m * sc;
    }
    __syncthreads();
    const int i4 = (blockIdx.x << 8) + t;             // 3125*256 == NN*64/4
    const float4 v = ((const float4*)y2)[i4];
    const int d0 = (i4 << 2) & 63;
    float4 o;
    o.x = fmaf(v.x, scshL[d0 + 0], scshL[64 + d0 + 0]);
    o.y = fmaf(v.y, scshL[d0 + 1], scshL[64 + d0 + 1]);
    o.z = fmaf(v.z, scshL[d0 + 2], scshL[64 + d0 + 2]);
    o.w = fmaf(v.w, scshL[d0 + 3], scshL[64 + d0 + 3]);
    ((float4*)out)[i4] = o;
}

extern "C" void kernel_launch(void* const* d_in, const int* in_sizes, int n_in,
                              void* d_out, int out_size, void* d_ws, size_t ws_size,
                              hipStream_t stream)
{
    const int*   x    = (const int*)d_in[0];
    const int*   ei   = (const int*)d_in[1];
    const float* ea   = (const float*)d_in[2];
    const float* nemb = (const float*)d_in[3];
    const float* We   = (const float*)d_in[4];
    const float* be   = (const float*)d_in[5];
    const float* eps  = (const float*)d_in[6];
    const float* W1   = (const float*)d_in[7];
    const float* b1   = (const float*)d_in[8];
    const float* g1   = (const float*)d_in[9];
    const float* bb1  = (const float*)d_in[10];
    const float* W2   = (const float*)d_in[11];
    const float* b2   = (const float*)d_in[12];
    const float* g2   = (const float*)d_in[13];
    const float* bb2  = (const float*)d_in[14];
    float* out = (float*)d_out;

    // workspace layout (4-byte word offsets)
    int*      iws   = (int*)d_ws;
    float*    fws   = (float*)d_ws;
    int*      off   = iws + 0;          // 50001
    int*      deg   = iws + 50048;      // 50000
    int*      bsum  = iws + 150144;     // 256 (raw padded bucket sums)
    int*      bktcur= iws + 150784;     // 196   } zeroed by one memset
    float*    accbuf= fws + 151040;     // 5*3072 (per layer: acc1 8x256 | acc2 8x128)
    _Float16* W1s   = (_Float16*)(fws + 451072);  // 5*8192 f16 swizzled
    _Float16* W2s   = (_Float16*)(fws + 471552);  // 5*8192 f16 swizzled
    unsigned* Wepk  = (unsigned*)(fws + 492032);  // 5*7*32 half2 (1120 words)
    unsigned* be2   = (unsigned*)(fws + 493152);  // 5*32 half2 (160 words)
    int4*     pea   = (int4*)(iws + 493312);      // 1,150,000 x 16B (padded CSR)
    _Float16* z16   = (_Float16*)(fws + 5093312); // 50048 x 64 f16 (padded rows)
    _Float16* y1h   = (_Float16*)(fws + 6694848); // 50048 x 128 f16 } row-
    float*    y2    = fws + 6694848;              // 50048 x 64 f32  } aliased
    __half*   h16   = (__half*)(fws + 9897920);   // 50001 x 64 f16 (+dummy row)

    // CSR-build staging aliases scratch consumed before the layer loop:
    //   srec: 196*4608 recs x 16B = 14.45 MB over z16+y1h region
    //   sdst: same recs x u16 = 1.8 MB over h16 region (place2 before prep)
    int4*           srec = (int4*)(fws + 5093312);
    unsigned short* sdst = (unsigned short*)(fws + 9897920);

    // zero bktcur + accbuf in one shot (adjacent: 150784..166400)
    hipMemsetAsync(bktcur, 0, (166400 - 150784) * sizeof(int), stream);

    bin_kernel    <<<196,  256, 0, stream>>>(ei, ea, bktcur, srec, sdst);
    bcountA_kernel<<<NBKT, 256, 0, stream>>>(bktcur, sdst, deg, bsum);
    scanC_kernel  <<<196,  256, 0, stream>>>(deg, bsum, off);
    place2_kernel <<<NBKT, 256, 0, stream>>>(bktcur, off, srec, sdst, pea);
    prep_kernel   <<<3450, 256, 0, stream>>>(x, nemb, h16, (unsigned*)z16,
                                             W1, W2, We, be, W1s, W2s, Wepk, be2);

    for (int l = 0; l < 5; ++l) {
        float* acc1 = accbuf + l * 3072;
        float* acc2 = accbuf + l * 3072 + 2048;

        gather_kernel<<<12500, 256, 0, stream>>>(
            off, pea, (const unsigned*)h16, Wepk + l * 224, be2 + l * 32,
            eps + l, (unsigned*)z16);

        mm1_kernel<<<NB, 256, 0, stream>>>(z16, W1s + l * 8192, b1 + l * 128,
                                           y1h, acc1);

        mm2_kernel<<<NB, 256, 0, stream>>>(y1h, acc1, g1 + l * 128, bb1 + l * 128,
                                           W2s + l * 8192, b2 + l * 64, y2, acc2);

        if (l < 4)
            hprep_kernel<<<3125, 256, 0, stream>>>(y2, acc2, g2 + l * 64,
                                                   bb2 + l * 64, h16);
    }

    final_kernel<<<3125, 256, 0, stream>>>(y2, accbuf + 4 * 3072 + 2048,
                                           g2 + 4 * 64, bb2 + 4 * 64, out);
}

// Round 12
// 408.904 us; speedup vs baseline: 1.0616x; 1.0616x over previous
//
#include <hip/hip_runtime.h>
#include <hip/hip_fp16.h>

#define NN 50000
#define EE 800000
#define NB 782      // blocks in mm1/mm2 grids
#define NBKT 196    // dst>>8 buckets (256 nodes each)
#define BCAP 4608   // staging capacity per bucket (mean 4081, +8 sigma)
#define PSLOT 6144  // fixed pea region per bucket (mean padded 5036, +17 sigma)

typedef _Float16 f16x8 __attribute__((ext_vector_type(8)));
typedef _Float16 f16x2 __attribute__((ext_vector_type(2)));
typedef float f32x4 __attribute__((ext_vector_type(4)));

// bit-cast helpers
__device__ __forceinline__ unsigned h2u(__half2 h) {
    union { __half2 h; unsigned u; } c; c.h = h; return c.u;
}
__device__ __forceinline__ f16x2 u2h(unsigned u) {
    union { unsigned u; f16x2 h; } c; c.u = u; return c.h;
}

// ---------------------------------------------------------------------------
// CSR build: bin (stage by dst>>8) -> buildB (per-bucket: hist -> local scan
// -> offSE{start,end} -> place -> dummy fill). Buckets own FIXED pea regions
// (PSLOT slots), so no cross-bucket scan exists. Dummy edge = {ea=0,
// src=50000}; h16 row 50000 = -65504 so relu(h_dummy+ee)==0 -> maskless
// gather.
// ---------------------------------------------------------------------------
__global__ __launch_bounds__(256) void bin_kernel(
    const int* __restrict__ ei, const float* __restrict__ ea,
    int* __restrict__ bktcur, int4* __restrict__ srec,
    unsigned short* __restrict__ sdst)
{
    __shared__ int cnt[NBKT], base[NBKT];
    const int t = threadIdx.x;
    if (t < NBKT) cnt[t] = 0;
    __syncthreads();
    const int e0 = blockIdx.x << 12;     // 4096 edges/block, 196 blocks
    int meta[16];                        // rk<<16 | bk<<8 | loc  (rk<4096)
#pragma unroll
    for (int j = 0; j < 16; ++j) {
        const int e = e0 + (j << 8) + t;
        if (e < EE) {
            const int d = ei[EE + e];
            const int bk = d >> 8;
            const int rk = atomicAdd(&cnt[bk], 1);
            meta[j] = (rk << 16) | (bk << 8) | (d & 255);
        } else meta[j] = -1;
    }
    __syncthreads();
    if (t < NBKT) base[t] = cnt[t] ? atomicAdd(&bktcur[t], cnt[t]) : 0;
    __syncthreads();
#pragma unroll
    for (int j = 0; j < 16; ++j) {
        if (meta[j] < 0) continue;
        const int bk = (meta[j] >> 8) & 255;
        const int slot = base[bk] + (meta[j] >> 16);
        if (slot >= BCAP) continue;      // statistically impossible guard
        const int pos = bk * BCAP + slot;
        const int e = e0 + (j << 8) + t;
        const int src = ei[e];
        const float* a = ea + e * 7;
        const unsigned h0 = __half_as_ushort(__float2half(a[0]));
        const unsigned h1 = __half_as_ushort(__float2half(a[1]));
        const unsigned h2 = __half_as_ushort(__float2half(a[2]));
        const unsigned h3 = __half_as_ushort(__float2half(a[3]));
        const unsigned h4 = __half_as_ushort(__float2half(a[4]));
        const unsigned h5 = __half_as_ushort(__float2half(a[5]));
        const unsigned h6 = __half_as_ushort(__float2half(a[6]));
        srec[pos] = make_int4((int)(h0 | (h1 << 16)), (int)(h2 | (h3 << 16)),
                              (int)(h4 | (h5 << 16)), (int)(h6 | ((unsigned)src << 16)));
        sdst[pos] = (unsigned short)(meta[j] & 255);
    }
}

// per-bucket: hist -> padded local scan -> offSE -> place -> dummy fill.
// Replaces bcountA + scanB + scanC + place2 (all logic bucket-local).
__global__ __launch_bounds__(256) void buildB_kernel(
    const int* __restrict__ bktcur, const int4* __restrict__ srec,
    const unsigned short* __restrict__ sdst,
    int2* __restrict__ offSE, int4* __restrict__ pea)
{
    __shared__ int nc[256], sm[256], curs[256];
    const int b = blockIdx.x, t = threadIdx.x;
    nc[t] = 0;
    __syncthreads();
    const int nE = min(bktcur[b], BCAP);
    const int sb = b * BCAP;
    for (int i = t; i < nE; i += 256) atomicAdd(&nc[(int)sdst[sb + i]], 1);
    __syncthreads();
    const int node = (b << 8) + t;
    const int used = nc[t];
    const int pd = (node < NN) ? ((used + 7) & ~7) : 0;   // padded degree
    sm[t] = pd;
    __syncthreads();
    for (int o = 1; o < 256; o <<= 1) {
        const int u = (t >= o) ? sm[t - o] : 0;
        __syncthreads();
        sm[t] += u;
        __syncthreads();
    }
    const int st = b * PSLOT + sm[t] - pd;   // bucket-local exclusive prefix
    if (node < NN) offSE[node] = make_int2(st, st + pd);
    curs[t] = st;
    __syncthreads();
    for (int i = t; i < nE; i += 256) {
        const int ln = (int)sdst[sb + i];
        const int p = atomicAdd(&curs[ln], 1);
        pea[p] = srec[sb + i];           // random only within ~96KB L2-hot slice
    }
    __syncthreads();
    if (node < NN) {
        const int end = st + pd;
        for (int p = curs[t]; p < end; ++p)   // dummy tail: relu(h_dummy+ee)==0
            pea[p] = make_int4(0, 0, 0, (int)(((unsigned)NN) << 16));
    }
}

// ---------------------------------------------------------------------------
// Prep (merged wprep + hprep0): blocks 0..3124 do layer-0 h16 = f16(nemb[x])
// (+ dummy row -65504, + z16 tail zero); blocks 3125..3449 do W prep.
// ---------------------------------------------------------------------------
__global__ __launch_bounds__(256) void prep_kernel(
    const int* __restrict__ x, const float* __restrict__ nemb,
    __half* __restrict__ h16, unsigned* __restrict__ z32,
    const float* __restrict__ W1, const float* __restrict__ W2,
    const float* __restrict__ We, const float* __restrict__ be,
    _Float16* __restrict__ W1s, _Float16* __restrict__ W2s,
    unsigned* __restrict__ Wepk, unsigned* __restrict__ be2)
{
    if (blockIdx.x < 3125) {
        const int i4 = (blockIdx.x << 8) + threadIdx.x;   // NN*64/4
        if (blockIdx.x == 0 && threadIdx.x < 32)
            ((unsigned*)h16)[(NN << 5) + threadIdx.x] = 0xFBFFFBFFu;
        if (i4 < 1536) z32[1600000 + i4] = 0u;   // zero z16 rows 50000..50047
        const int n = i4 >> 4;
        const float4 v = ((const float4*)nemb)[(x[n] << 4) + (i4 & 15)];
        *(int2*)(h16 + (i4 << 2)) =
            make_int2((int)h2u(__floats2half2_rn(v.x, v.y)),
                      (int)h2u(__floats2half2_rn(v.z, v.w)));
        return;
    }
    const int i = ((blockIdx.x - 3125) << 8) + threadIdx.x;
    if (i < 40960) {
        const int l = i >> 13, j = i & 8191, k = j >> 7, n = j & 127;
        W1s[(l << 13) + ((((k >> 3) << 7) + n) << 3) + (k & 7)] = (_Float16)W1[i];
    } else if (i < 81920) {
        const int i2 = i - 40960;
        const int l = i2 >> 13, j = i2 & 8191, k = j >> 6, n = j & 63;
        W2s[(l << 13) + ((((k >> 3) << 6) + n) << 3) + (k & 7)] = (_Float16)W2[i2];
    } else if (i < 83040) {
        const int i3 = i - 81920;            // 0..1119 = [l][k][s]
        const int l = i3 / 224;
        const int r = i3 - l * 224;
        const int k = r >> 5, s = r & 31;
        const float* W = We + l * 448 + (k << 6) + (s << 1);
        Wepk[i3] = h2u(__floats2half2_rn(W[0], W[1]));
    } else if (i < 83200) {
        const int i4 = i - 83040;            // 0..159 = [l][s]
        const int l = i4 >> 5, s = i4 & 31;
        const float* B = be + (l << 6) + (s << 1);
        be2[i4] = h2u(__floats2half2_rn(B[0], B[1]));
    }
}

// ---------------------------------------------------------------------------
// h-prep: h16 = f16(relu(bn2(y2))). BN2 scale/shift computed in-block from
// the 8-way-split atomic accumulators (acc2: 8 copies x [s64|q64]).
// ---------------------------------------------------------------------------
__global__ __launch_bounds__(256) void hprep_kernel(
    const float* __restrict__ y2, const float* __restrict__ acc2,
    const float* __restrict__ g2p, const float* __restrict__ bb2p,
    __half* __restrict__ h16)
{
    __shared__ float scshL[128];
    const int t = threadIdx.x;
    if (t < 64) {
        float ss = 0.f, qq = 0.f;
#pragma unroll
        for (int c = 0; c < 8; ++c) {
            ss += acc2[(c << 7) + t];
            qq += acc2[(c << 7) + 64 + t];
        }
        const float m = ss * (1.0f / NN);
        const float v = fmaxf(qq * (1.0f / NN) - m * m, 0.0f);
        const float sc = g2p[t] * rsqrtf(v + 1e-5f);
        scshL[t] = sc;
        scshL[64 + t] = bb2p[t] - m * sc;
    }
    __syncthreads();
    const int i4 = (blockIdx.x << 8) + t;             // 3125*256 == NN*64/4
    const float4 v = ((const float4*)y2)[i4];
    const int d0 = (i4 << 2) & 63;
    const float a = fmaxf(fmaf(v.x, scshL[d0 + 0], scshL[64 + d0 + 0]), 0.f);
    const float b = fmaxf(fmaf(v.y, scshL[d0 + 1], scshL[64 + d0 + 1]), 0.f);
    const float c = fmaxf(fmaf(v.z, scshL[d0 + 2], scshL[64 + d0 + 2]), 0.f);
    const float d = fmaxf(fmaf(v.w, scshL[d0 + 3], scshL[64 + d0 + 3]), 0.f);
    *(int2*)(h16 + (i4 << 2)) =
        make_int2((int)h2u(__floats2half2_rn(a, b)),
                  (int)h2u(__floats2half2_rn(c, d)));
}

// ---------------------------------------------------------------------------
// Gather (r9-proven): 2 nodes/wave, lane owns 2 dims (half2). CSR padded to
// x8 with dummy edges (msg==0). 16-edge batches (32 loads in flight); odd
// 8-batch peeled. Per-node {start,end} from offSE.
// ---------------------------------------------------------------------------
__global__ __launch_bounds__(256) void gather_kernel(
    const int2* __restrict__ offSE, const int4* __restrict__ pea,
    const unsigned* __restrict__ h32,      // h16 rows viewed as 32 dwords
    const unsigned* __restrict__ Wepk, const unsigned* __restrict__ be2,
    const float* __restrict__ epsp,
    unsigned* __restrict__ z32)            // z16 rows viewed as 32 dwords
{
    const int t = threadIdx.x;
    const int lane = t & 63;
    const int s = lane & 31;
    const int n = (blockIdx.x << 3) + ((t >> 6) << 1) + (lane >> 5); // 6250*8

    const f16x2 w0 = u2h(Wepk[s]),       w1 = u2h(Wepk[32 + s]),
                w2 = u2h(Wepk[64 + s]),  w3 = u2h(Wepk[96 + s]),
                w4 = u2h(Wepk[128 + s]), w5 = u2h(Wepk[160 + s]),
                w6 = u2h(Wepk[192 + s]);
    const f16x2 beh = u2h(be2[s]);

    const int2 se = offSE[n];
    const int e0 = se.x, e1 = se.y;        // padded: count % 8 == 0

    f16x2 acc2 = (f16x2){(_Float16)0.f, (_Float16)0.f};
    int e = e0;
    if (((e1 - e0) >> 3) & 1) {            // peel one 8-batch if odd count
        int4 pk[8];
#pragma unroll
        for (int j = 0; j < 8; ++j) pk[j] = pea[e + j];
        unsigned hv[8];
#pragma unroll
        for (int j = 0; j < 8; ++j)
            hv[j] = h32[(((int)(((unsigned)pk[j].w) >> 16)) << 5) + s];
#pragma unroll
        for (int j = 0; j < 8; ++j) {
            const f16x2 a01 = u2h((unsigned)pk[j].x);
            const f16x2 a23 = u2h((unsigned)pk[j].y);
            const f16x2 a45 = u2h((unsigned)pk[j].z);
            const f16x2 a6x = u2h((unsigned)pk[j].w);
            f16x2 ee = beh;
            ee += (f16x2){a01[0], a01[0]} * w0;
            ee += (f16x2){a01[1], a01[1]} * w1;
            ee += (f16x2){a23[0], a23[0]} * w2;
            ee += (f16x2){a23[1], a23[1]} * w3;
            ee += (f16x2){a45[0], a45[0]} * w4;
            ee += (f16x2){a45[1], a45[1]} * w5;
            ee += (f16x2){a6x[0], a6x[0]} * w6;
            f16x2 m2 = u2h(hv[j]) + ee;
            const _Float16 zz = (_Float16)0.f;
            m2 = (f16x2){ m2[0] > zz ? m2[0] : zz, m2[1] > zz ? m2[1] : zz };
            acc2 += m2;
        }
        e += 8;
    }
    for (; e < e1; e += 16) {              // 16-edge batches: 32 loads in flight
        int4 pk[16];
#pragma unroll
        for (int j = 0; j < 16; ++j) pk[j] = pea[e + j];
        unsigned hv[16];
#pragma unroll
        for (int j = 0; j < 16; ++j)
            hv[j] = h32[(((int)(((unsigned)pk[j].w) >> 16)) << 5) + s];
#pragma unroll
        for (int j = 0; j < 16; ++j) {
            const f16x2 a01 = u2h((unsigned)pk[j].x);
            const f16x2 a23 = u2h((unsigned)pk[j].y);
            const f16x2 a45 = u2h((unsigned)pk[j].z);
            const f16x2 a6x = u2h((unsigned)pk[j].w);
            f16x2 ee = beh;
            ee += (f16x2){a01[0], a01[0]} * w0;
            ee += (f16x2){a01[1], a01[1]} * w1;
            ee += (f16x2){a23[0], a23[0]} * w2;
            ee += (f16x2){a23[1], a23[1]} * w3;
            ee += (f16x2){a45[0], a45[0]} * w4;
            ee += (f16x2){a45[1], a45[1]} * w5;
            ee += (f16x2){a6x[0], a6x[0]} * w6;
            f16x2 m2 = u2h(hv[j]) + ee;
            const _Float16 zz = (_Float16)0.f;
            m2 = (f16x2){ m2[0] > zz ? m2[0] : zz, m2[1] > zz ? m2[1] : zz };
            acc2 += m2;
        }
    }
    const f16x2 hn2 = u2h(h32[(n << 5) + s]);
    const float e1f = 1.0f + epsp[0];
    const float zLo = fmaf(e1f, (float)hn2[0], (float)acc2[0]);
    const float zHi = fmaf(e1f, (float)hn2[1], (float)acc2[1]);
    z32[(n << 5) + s] = h2u(__floats2half2_rn(zLo, zHi));
}

// ---------------------------------------------------------------------------
// MM1 (MFMA f16): y1 = z16 @ W1 + b1, f16 out. Block = 64 rows, 4 waves.
// BN1 block sums -> 8-way-split global f32 atomics (no fence).
// ---------------------------------------------------------------------------
__global__ __launch_bounds__(256) void mm1_kernel(
    const _Float16* __restrict__ z16, const _Float16* __restrict__ W1s,
    const float* __restrict__ b1p, _Float16* __restrict__ y1h,
    float* __restrict__ acc1)
{
    __shared__ float smS[4][128], smQ[4][128];
    const int t = threadIdx.x;
    const int wv = t >> 6, lane = t & 63;
    const int q = lane >> 4, ln = lane & 15;
    const int r0 = blockIdx.x << 6;

    const int rowm = r0 + (wv << 4) + ln;
    const f16x8 af0 = *(const f16x8*)(z16 + rowm * 64 + (q << 3));
    const f16x8 af1 = *(const f16x8*)(z16 + rowm * 64 + 32 + (q << 3));

    f32x4 acc[8];
#pragma unroll
    for (int n0 = 0; n0 < 8; ++n0) acc[n0] = (f32x4){0.f, 0.f, 0.f, 0.f};
#pragma unroll
    for (int n0 = 0; n0 < 8; ++n0) {
        const f16x8 bf0 = *(const f16x8*)(W1s + (((q << 7) + (n0 << 4) + ln) << 3));
        const f16x8 bf1 = *(const f16x8*)(W1s + ((((4 + q) << 7) + (n0 << 4) + ln) << 3));
        acc[n0] = __builtin_amdgcn_mfma_f32_16x16x32_f16(af0, bf0, acc[n0], 0, 0, 0);
        acc[n0] = __builtin_amdgcn_mfma_f32_16x16x32_f16(af1, bf1, acc[n0], 0, 0, 0);
    }

    const int baseRow = r0 + (wv << 4) + (q << 2);
#pragma unroll
    for (int n0 = 0; n0 < 8; ++n0) {
        const int col = (n0 << 4) + ln;
        const float bb = b1p[col];
        float s = 0.f, sq = 0.f;
#pragma unroll
        for (int rg = 0; rg < 4; ++rg) {
            const int row = baseRow + rg;
            const float y = acc[n0][rg] + bb;
            y1h[row * 128 + col] = (_Float16)y;
            const float m = (row < NN) ? 1.f : 0.f;
            s = fmaf(m, y, s); sq = fmaf(m, y * y, sq);
        }
        s += __shfl_xor(s, 16); s += __shfl_xor(s, 32);
        sq += __shfl_xor(sq, 16); sq += __shfl_xor(sq, 32);
        if (lane < 16) { smS[wv][col] = s; smQ[wv][col] = sq; }
    }
    __syncthreads();
    if (t < 128) {
        const float s4 = smS[0][t] + smS[1][t] + smS[2][t] + smS[3][t];
        const float q4 = smQ[0][t] + smQ[1][t] + smQ[2][t] + smQ[3][t];
        float* a1 = acc1 + ((blockIdx.x & 7) << 8);
        atomicAdd(&a1[t], s4);
        atomicAdd(&a1[128 + t], q4);
    }
}

// ---------------------------------------------------------------------------
// MM2 (MFMA f16): y2 = relu(bn1(y1h)) @ W2 + b2 (f32 out). Block = 64 rows.
// Prologue: per-block reduce of acc1 -> scsh1 in LDS. Epilogue: BN2 -> acc2.
// ---------------------------------------------------------------------------
__global__ __launch_bounds__(256) void mm2_kernel(
    const _Float16* __restrict__ y1h, const float* __restrict__ acc1,
    const float* __restrict__ g1p, const float* __restrict__ bb1p,
    const _Float16* __restrict__ W2s, const float* __restrict__ b2,
    float* __restrict__ y2, float* __restrict__ acc2)
{
    __shared__ float smS[4][64], smQ[4][64];
    __shared__ float scshL[256];
    const int t = threadIdx.x;
    const int wv = t >> 6, lane = t & 63;
    const int q = lane >> 4, ln = lane & 15;
    const int r0 = blockIdx.x << 6;

    if (t < 128) {                       // finalize BN1 from acc1 (3KB read)
        float ss = 0.f, qq = 0.f;
#pragma unroll
        for (int c = 0; c < 8; ++c) {
            ss += acc1[(c << 8) + t];
            qq += acc1[(c << 8) + 128 + t];
        }
        const float m = ss * (1.0f / NN);
        const float v = fmaxf(qq * (1.0f / NN) - m * m, 0.0f);
        const float sc = g1p[t] * rsqrtf(v + 1e-5f);
        scshL[t] = sc;
        scshL[128 + t] = bb1p[t] - m * sc;
    }
    __syncthreads();

    const int rowm = r0 + (wv << 4) + ln;
    f16x8 af[4];
#pragma unroll
    for (int ks = 0; ks < 4; ++ks) {
        const int k0 = (ks << 5) + (q << 3);
        const f16x8 raw = *(const f16x8*)(y1h + rowm * 128 + k0);
        f16x8 a;
#pragma unroll
        for (int j = 0; j < 8; ++j) {
            const float sc = scshL[k0 + j], sh = scshL[128 + k0 + j];
            a[j] = (_Float16)fmaxf(fmaf((float)raw[j], sc, sh), 0.f);
        }
        af[ks] = a;
    }

    f32x4 acc[4];
#pragma unroll
    for (int n0 = 0; n0 < 4; ++n0) acc[n0] = (f32x4){0.f, 0.f, 0.f, 0.f};
#pragma unroll
    for (int n0 = 0; n0 < 4; ++n0) {
#pragma unroll
        for (int ks = 0; ks < 4; ++ks) {
            const f16x8 bf = *(const f16x8*)(
                W2s + (((((ks << 2) + q) << 6) + (n0 << 4) + ln) << 3));
            acc[n0] = __builtin_amdgcn_mfma_f32_16x16x32_f16(af[ks], bf, acc[n0], 0, 0, 0);
        }
    }

    const int baseRow = r0 + (wv << 4) + (q << 2);
#pragma unroll
    for (int n0 = 0; n0 < 4; ++n0) {
        const int col = (n0 << 4) + ln;
        const float bb = b2[col];
        float sa = 0.f, sq = 0.f;
#pragma unroll
        for (int rg = 0; rg < 4; ++rg) {
            const int row = baseRow + rg;
            const float y = acc[n0][rg] + bb;
            y2[row * 64 + col] = y;
            const float m = (row < NN) ? 1.f : 0.f;
            sa = fmaf(m, y, sa); sq = fmaf(m, y * y, sq);
        }
        sa += __shfl_xor(sa, 16); sa += __shfl_xor(sa, 32);
        sq += __shfl_xor(sq, 16); sq += __shfl_xor(sq, 32);
        if (lane < 16) { smS[wv][col] = sa; smQ[wv][col] = sq; }
    }
    __syncthreads();
    if (t < 64) {
        const float s4 = smS[0][t] + smS[1][t] + smS[2][t] + smS[3][t];
        const float q4 = smQ[0][t] + smQ[1][t] + smQ[2][t] + smQ[3][t];
        float* a2 = acc2 + ((blockIdx.x & 7) << 7);
        atomicAdd(&a2[t], s4);
        atomicAdd(&a2[64 + t], q4);
    }
}

// ---------------------------------------------------------------------------
// Final: out = bn2(y2) of layer 4 (no relu). BN2 finalized in-block.
// ---------------------------------------------------------------------------
__global__ __launch_bounds__(256) void final_kernel(
    const float* __restrict__ y2, const float* __restrict__ acc2,
    const float* __restrict__ g2p, const float* __restrict__ bb2p,
    float* __restrict__ out)
{
    __shared__ float scshL[128];
    const int t = threadIdx.x;
    if (t < 64) {
        float ss = 0.f, qq = 0.f;
#pragma unroll
        for (int c = 0; c < 8; ++c) {
            ss += acc2[(c << 7) + t];
            qq += acc2[(c << 7) + 64 + t];
        }
        const float m = ss * (1.0f / NN);
        const float v = fmaxf(qq * (1.0f / NN) - m * m, 0.0f);
        const float sc = g2p[t] * rsqrtf(v + 1e-5f);
        scshL[t] = sc;
        scshL[64 + t] = bb2p[t] - m * sc;
    }
    __syncthreads();
    const int i4 = (blockIdx.x << 8) + t;             // 3125*256 == NN*64/4
    const float4 v = ((const float4*)y2)[i4];
    const int d0 = (i4 << 2) & 63;
    float4 o;
    o.x = fmaf(v.x, scshL[d0 + 0], scshL[64 + d0 + 0]);
    o.y = fmaf(v.y, scshL[d0 + 1], scshL[64 + d0 + 1]);
    o.z = fmaf(v.z, scshL[d0 + 2], scshL[64 + d0 + 2]);
    o.w = fmaf(v.w, scshL[d0 + 3], scshL[64 + d0 + 3]);
    ((float4*)out)[i4] = o;
}

extern "C" void kernel_launch(void* const* d_in, const int* in_sizes, int n_in,
                              void* d_out, int out_size, void* d_ws, size_t ws_size,
                              hipStream_t stream)
{
    const int*   x    = (const int*)d_in[0];
    const int*   ei   = (const int*)d_in[1];
    const float* ea   = (const float*)d_in[2];
    const float* nemb = (const float*)d_in[3];
    const float* We   = (const float*)d_in[4];
    const float* be   = (const float*)d_in[5];
    const float* eps  = (const float*)d_in[6];
    const float* W1   = (const float*)d_in[7];
    const float* b1   = (const float*)d_in[8];
    const float* g1   = (const float*)d_in[9];
    const float* bb1  = (const float*)d_in[10];
    const float* W2   = (const float*)d_in[11];
    const float* b2   = (const float*)d_in[12];
    const float* g2   = (const float*)d_in[13];
    const float* bb2  = (const float*)d_in[14];
    float* out = (float*)d_out;

    // workspace layout (4-byte word offsets); total ~11,379,968 words = 45.5MB
    int*      iws   = (int*)d_ws;
    float*    fws   = (float*)d_ws;
    int2*     offSE = (int2*)iws;                 // 0: 50000 x int2 (100,000 w)
    int*      bktcur= iws + 100096;               // 196   } zeroed by one memset
    float*    accbuf= fws + 100352;               // 5*3072 -> ends 115,712
    _Float16* W1s   = (_Float16*)(fws + 115712);  // 5*8192 f16 swizzled
    _Float16* W2s   = (_Float16*)(fws + 136192);  // 5*8192 f16 swizzled
    unsigned* Wepk  = (unsigned*)(fws + 156672);  // 5*7*32 half2 (1120 words)
    unsigned* be2   = (unsigned*)(fws + 157792);  // 5*32 half2 (160 words)
    int4*     pea   = (int4*)(iws + 157952);      // 196*6144 x 16B fixed regions
    _Float16* z16   = (_Float16*)(fws + 4974848); // 50048 x 64 f16 (padded rows)
    _Float16* y1h   = (_Float16*)(fws + 6576384); // 50048 x 128 f16 } row-
    float*    y2    = fws + 6576384;              // 50048 x 64 f32  } aliased
    __half*   h16   = (__half*)(fws + 9779456);   // 50001 x 64 f16 (+dummy row)

    // CSR-build staging aliases scratch consumed before the layer loop:
    //   srec: 196*4608 recs x 16B = 14.45 MB over z16+y1h region
    //   sdst: same recs x u16 = 1.8 MB over h16 region (buildB before prep)
    int4*           srec = (int4*)(fws + 4974848);
    unsigned short* sdst = (unsigned short*)(fws + 9779456);

    // zero bktcur + accbuf in one shot (adjacent: 100096..115712)
    hipMemsetAsync(bktcur, 0, (115712 - 100096) * sizeof(int), stream);

    bin_kernel   <<<196,  256, 0, stream>>>(ei, ea, bktcur, srec, sdst);
    buildB_kernel<<<NBKT, 256, 0, stream>>>(bktcur, srec, sdst, offSE, pea);
    prep_kernel  <<<3450, 256, 0, stream>>>(x, nemb, h16, (unsigned*)z16,
                                            W1, W2, We, be, W1s, W2s, Wepk, be2);

    for (int l = 0; l < 5; ++l) {
        float* acc1 = accbuf + l * 3072;
        float* acc2 = accbuf + l * 3072 + 2048;

        gather_kernel<<<6250, 256, 0, stream>>>(
            offSE, pea, (const unsigned*)h16, Wepk + l * 224, be2 + l * 32,
            eps + l, (unsigned*)z16);

        mm1_kernel<<<NB, 256, 0, stream>>>(z16, W1s + l * 8192, b1 + l * 128,
                                           y1h, acc1);

        mm2_kernel<<<NB, 256, 0, stream>>>(y1h, acc1, g1 + l * 128, bb1 + l * 128,
                                           W2s + l * 8192, b2 + l * 64, y2, acc2);

        if (l < 4)
            hprep_kernel<<<3125, 256, 0, stream>>>(y2, acc2, g2 + l * 64,
                                                   bb2 + l * 64, h16);
    }

    final_kernel<<<3125, 256, 0, stream>>>(y2, accbuf + 4 * 3072 + 2048,
                                           g2 + 4 * 64, bb2 + 4 * 64, out);
}